// Round 1
// baseline (2449.911 us; speedup 1.0000x reference)
//
#include <hip/hip_runtime.h>
#include <math.h>

#define Dm 768
#define Tn 8
#define Nn 197
#define Sn 1576
#define MLPn 3072
#define NPn 196
#define MPAD 1664   // 13*128

typedef unsigned short u16;
typedef __bf16 bf16x8 __attribute__((ext_vector_type(8)));
typedef float f32x4 __attribute__((ext_vector_type(4)));
typedef unsigned int u32x4 __attribute__((ext_vector_type(4)));
typedef u16 u16x8 __attribute__((ext_vector_type(8)));
typedef u16 u16x4 __attribute__((ext_vector_type(4)));

__device__ inline u16 f2bf(float f) {
    union { float f; unsigned u; } v; v.f = f;
    unsigned r = v.u + 0x7fffu + ((v.u >> 16) & 1u);
    return (u16)(r >> 16);
}
__device__ inline float bf2f(u16 v) {
    union { unsigned u; float f; } x; x.u = ((unsigned)v) << 16; return x.f;
}

// async global->LDS, 16B per lane. LDS dest is wave-uniform base + lane*16.
__device__ __forceinline__ void gl_lds16(const u16* __restrict__ g, u16* l) {
    __builtin_amdgcn_global_load_lds((const __attribute__((address_space(1))) void*)g,
                                     (__attribute__((address_space(3))) void*)l,
                                     16, 0, 0);
}

// ---------------- im2col: x[1,8,3,224,224] -> P[1568,768] bf16 ----------------
__global__ __launch_bounds__(256) void im2col_k(const float* __restrict__ x, u16* __restrict__ P) {
    int idx = blockIdx.x * 256 + threadIdx.x;
    if (idx >= 1568 * 768) return;
    int c = idx % 768, r = idx / 768;
    int p = r % 196, t = r / 196;
    int hp = p / 14, wp = p % 14;
    int ch = c / 256, rem = c % 256, py = rem / 16, px = rem % 16;
    P[idx] = f2bf(x[((t * 3 + ch) * 224 + hp * 16 + py) * 224 + wp * 16 + px]);
}

__global__ __launch_bounds__(256) void cvt_k(const float* __restrict__ s, u16* __restrict__ d, int n) {
    int i = blockIdx.x * 256 + threadIdx.x;
    if (i < n) d[i] = f2bf(s[i]);
}

// ---------------- per-layer weight transpose+convert: fp32 [K,N] -> bf16 [N,K] ----------------
__global__ __launch_bounds__(256) void cvtT_layer_k(const float* __restrict__ qw, const float* __restrict__ pw,
                                                    const float* __restrict__ f1w, const float* __restrict__ f2w,
                                                    u16* __restrict__ Wq, u16* __restrict__ Wp,
                                                    u16* __restrict__ W1, u16* __restrict__ W2) {
    __shared__ float tile[32][33];
    int bid = blockIdx.x;
    const float* src; u16* dst; int K, N, k0, n0;
    if (bid < 1728)      { src = qw;  dst = Wq; K = 768;  N = 2304; int r = bid;        k0 = (r / 72) * 32; n0 = (r % 72) * 32; }
    else if (bid < 2304) { src = pw;  dst = Wp; K = 768;  N = 768;  int r = bid - 1728; k0 = (r / 24) * 32; n0 = (r % 24) * 32; }
    else if (bid < 4608) { src = f1w; dst = W1; K = 768;  N = 3072; int r = bid - 2304; k0 = (r / 96) * 32; n0 = (r % 96) * 32; }
    else                 { src = f2w; dst = W2; K = 3072; N = 768;  int r = bid - 4608; k0 = (r / 24) * 32; n0 = (r % 24) * 32; }
    int tx = threadIdx.x & 31, ty = threadIdx.x >> 5;
#pragma unroll
    for (int i = 0; i < 4; ++i) tile[ty + 8 * i][tx] = src[(size_t)(k0 + ty + 8 * i) * N + n0 + tx];
    __syncthreads();
#pragma unroll
    for (int i = 0; i < 4; ++i) dst[(size_t)(n0 + ty + 8 * i) * K + k0 + tx] = f2bf(tile[tx][ty + 8 * i]);
}

// ---------------- scramble + cls + pos -> h[1576,768] fp32 ----------------
__global__ __launch_bounds__(256) void build_h_k(const float* __restrict__ emb, const float* __restrict__ cls,
                                                 const float* __restrict__ pos, float* __restrict__ h) {
    int idx = blockIdx.x * 256 + threadIdx.x;
    if (idx >= Sn * Dm) return;
    int d = idx % Dm, s = idx / Dm;
    int t = s / Nn, r = s % Nn;
    float v;
    if (r == 0) v = cls[d];
    else {
        int f = (r - 1) * Dm + d;
        int p = f % NPn, dd = f / NPn;
        v = emb[(size_t)(t * NPn + p) * Dm + dd];
    }
    h[idx] = v + pos[r * Dm + d];
}

// ---------------- LayerNorm ----------------
template <typename OutT>
__global__ __launch_bounds__(256) void ln_k(const float* __restrict__ X, const float* __restrict__ g,
                                            const float* __restrict__ bta, OutT* __restrict__ Y) {
    int row = blockIdx.x;
    const float* x = X + (size_t)row * Dm;
    float s = 0.f, s2 = 0.f;
#pragma unroll
    for (int q = 0; q < 3; ++q) {
        float v = x[threadIdx.x + q * 256];
        s += v; s2 += v * v;
    }
#pragma unroll
    for (int off = 1; off < 64; off <<= 1) {
        s  += __shfl_xor(s,  off);
        s2 += __shfl_xor(s2, off);
    }
    __shared__ float red[8];
    int wv = threadIdx.x >> 6;
    if ((threadIdx.x & 63) == 0) { red[wv * 2] = s; red[wv * 2 + 1] = s2; }
    __syncthreads();
    s  = red[0] + red[2] + red[4] + red[6];
    s2 = red[1] + red[3] + red[5] + red[7];
    float mu  = s * (1.f / 768.f);
    float var = s2 * (1.f / 768.f) - mu * mu;
    float rstd = rsqrtf(var + 1e-5f);
#pragma unroll
    for (int q = 0; q < 3; ++q) {
        int i = threadIdx.x + q * 256;
        float v = (x[i] - mu) * rstd * g[i] + bta[i];
        if constexpr (sizeof(OutT) == 2) Y[(size_t)row * Dm + i] = f2bf(v);
        else                             Y[(size_t)row * Dm + i] = v;
    }
}

// ---------------- MFMA bf16 GEMM, split-K: Cp[split][MPAD][N] = A@Bt^T over K-chunk ----------------
// Staging via global_load_lds (async DMA, no VGPR roundtrip). LDS layout is linear
// chunk c -> byte c*16, which is exactly wave-uniform base (w*1024) + lane*16.
__global__ __launch_bounds__(256) void mgemm_k(const u16* __restrict__ A, const u16* __restrict__ Bt,
                                               float* __restrict__ Cp, int N, int Kfull, int Kc) {
    __shared__ __align__(16) u16 As[4096];
    __shared__ __align__(16) u16 Bs[4096];
    int split = blockIdx.z;
    A  += split * Kc;
    Bt += split * Kc;
    Cp += (size_t)split * MPAD * N;
    int tid = threadIdx.x;
    int lane = tid & 63, w = tid >> 6;
    int wm = w & 1, wn = w >> 1;
    int m0 = blockIdx.y * 128, n0 = blockIdx.x * 128;
    f32x4 acc[4][4] = {};
    int c0 = tid, c1 = tid + 256;
    int ar0 = ((c0 >> 6) << 4) + (c0 & 15), ac0 = ((c0 >> 4) & 3) << 3;
    int ar1 = ((c1 >> 6) << 4) + (c1 & 15), ac1 = ((c1 >> 4) & 3) << 3;
    const u16* Arow0 = A  + (size_t)(m0 + ar0) * Kfull + ac0;
    const u16* Arow1 = A  + (size_t)(m0 + ar1) * Kfull + ac1;
    const u16* Brow0 = Bt + (size_t)(n0 + ar0) * Kfull + ac0;
    const u16* Brow1 = Bt + (size_t)(n0 + ar1) * Kfull + ac1;
    // wave-uniform LDS bases (u16 units: chunk_base*8 -> byte = chunk_base*16)
    u16* As0 = As + (w * 64) * 8;
    u16* As1 = As + (256 + w * 64) * 8;
    u16* Bs0 = Bs + (w * 64) * 8;
    u16* Bs1 = Bs + (256 + w * 64) * 8;
    for (int k0 = 0; k0 < Kc; k0 += 32) {
        gl_lds16(Arow0 + k0, As0);
        gl_lds16(Arow1 + k0, As1);
        gl_lds16(Brow0 + k0, Bs0);
        gl_lds16(Brow1 + k0, Bs1);
        __syncthreads();
        bf16x8 af[4], bfr[4];
#pragma unroll
        for (int i = 0; i < 4; ++i) {
            af[i]  = *(const bf16x8*)(As + (((wm * 4 + i) * 64 + lane) << 3));
            bfr[i] = *(const bf16x8*)(Bs + (((wn * 4 + i) * 64 + lane) << 3));
        }
#pragma unroll
        for (int mi = 0; mi < 4; ++mi)
#pragma unroll
            for (int ni = 0; ni < 4; ++ni)
                acc[mi][ni] = __builtin_amdgcn_mfma_f32_16x16x32_bf16(af[mi], bfr[ni], acc[mi][ni], 0, 0, 0);
        __syncthreads();
    }
    int rbase = (lane >> 4) << 2, cl = lane & 15;
#pragma unroll
    for (int mi = 0; mi < 4; ++mi)
#pragma unroll
        for (int r = 0; r < 4; ++r) {
            int gm = m0 + wm * 64 + mi * 16 + rbase + r;
#pragma unroll
            for (int ni = 0; ni < 4; ++ni) {
                int gn = n0 + wn * 64 + ni * 16 + cl;
                Cp[(size_t)gm * N + gn] = acc[mi][ni][r];
            }
        }
}

// ---------------- epilogue: sum splits + bias [+gelu] [+resid] -> OutT ----------------
template <bool GELU_ACT, bool RESID, typename OutT>
__global__ __launch_bounds__(256) void ep_k(const float* __restrict__ Cp, const float* __restrict__ bias,
                                            const float* __restrict__ resid, OutT* __restrict__ out,
                                            int N, int S) {
    int row = blockIdx.y;
    int n = blockIdx.x * 1024 + threadIdx.x * 4;
    if (n >= N) return;
    size_t off = (size_t)row * N + n;
    f32x4 acc = *(const f32x4*)(Cp + off);
    for (int s = 1; s < S; ++s)
        acc += *(const f32x4*)(Cp + (size_t)s * MPAD * N + off);
    acc += *(const f32x4*)(bias + n);
    if (GELU_ACT) {
#pragma unroll
        for (int j = 0; j < 4; ++j) acc[j] = 0.5f * acc[j] * (1.f + erff(acc[j] * 0.7071067811865476f));
    }
    if (RESID) acc += *(const f32x4*)(resid + off);
    if constexpr (sizeof(OutT) == 2) {
        u16x4 o;
#pragma unroll
        for (int j = 0; j < 4; ++j) o[j] = f2bf(acc[j]);
        *(u16x4*)((u16*)out + off) = o;
    } else {
        *(f32x4*)((float*)out + off) = acc;
    }
}

// ---------------- per-(head,frame) mean of V (bf16 input) ----------------
__global__ __launch_bounds__(64) void vmean_k(const u16* __restrict__ qkv, float* __restrict__ vm) {
    int g = blockIdx.x;      // g = h*8 + t
    int h = g >> 3, t = g & 7;
    int d = threadIdx.x;
    float s = 0.f;
    for (int n = 0; n < Nn; ++n)
        s += bf2f(qkv[(size_t)(t * Nn + n) * 2304 + 1536 + h * 64 + d]);
    vm[g * 64 + d] = s * (1.f / 197.f);
}

// ---------------- MFMA flash attention ----------------
// block: 4 waves x 32 queries = 128 queries, one (group, key-split). 64-key tiles.
// LDS: Ks[key][dim] bf16 swizzled; Vt[dim][key] bf16 swizzled; Ps per-wave P roundtrip.
// 16B-chunk swizzle: chunk c of row r stored at c ^ (r&7).
__global__ __launch_bounds__(256) void attn_mfma_k(const u16* __restrict__ qkv, float* __restrict__ Ou,
                                                   float* __restrict__ ml, int even, int nsplit,
                                                   int NG, int Sq) {
    __shared__ __align__(16) u16 Ks[64 * 64];
    __shared__ __align__(16) u16 Vt[64 * 64];
    __shared__ __align__(16) u16 Ps[4 * 32 * 64];
    int g = blockIdx.y;
    int h, sbase;
    if (even) { h = g >> 3; sbase = (g & 7) * Nn; } else { h = g; sbase = 0; }
    int split = blockIdx.z;
    int chunk = (Sq + nsplit - 1) / nsplit;
    int kbeg = split * chunk, kend = min(Sq, kbeg + chunk);
    int tid = threadIdx.x, lane = tid & 63, w = tid >> 6;
    int quad = lane >> 4, l15 = lane & 15;
    int q0w = blockIdx.x * 128 + w * 32;
    u16* Pw = Ps + w * 2048;

    // Q A-frags: A[m=l15 (query)][k=quad*8+j + ks*32 (dim)]
    bf16x8 aq[2][2];
#pragma unroll
    for (int mb = 0; mb < 2; ++mb) {
        int qidx = q0w + mb * 16 + l15; if (qidx >= Sq) qidx = Sq - 1;
        const u16* qp = qkv + (size_t)(sbase + qidx) * 2304 + h * 64;
#pragma unroll
        for (int ks = 0; ks < 2; ++ks)
            aq[mb][ks] = *(const bf16x8*)(qp + ks * 32 + quad * 8);
    }
    f32x4 acc_o[2][4] = {};
    float m_run[2][4], l_run[2][4];
#pragma unroll
    for (int mb = 0; mb < 2; ++mb)
#pragma unroll
        for (int r = 0; r < 4; ++r) { m_run[mb][r] = -INFINITY; l_run[mb][r] = 0.f; }

    for (int kt = kbeg; kt < kend; kt += 64) {
        int cnt = kend - kt; if (cnt > 64) cnt = 64;
        // ---- stage K (natural rows, swizzled chunks) ----
        {
            int dc = tid & 7;
#pragma unroll
            for (int p = 0; p < 2; ++p) {
                int row = (tid >> 3) + 32 * p;
                u32x4 kd = {};
                if (row < cnt) kd = *(const u32x4*)(qkv + (size_t)(sbase + kt + row) * 2304 + 768 + h * 64 + dc * 8);
                *(u32x4*)(Ks + row * 64 + ((dc ^ (row & 7)) << 3)) = kd;
            }
        }
        // ---- stage Vt (transposed, swizzled) ----
        {
            int d = (tid & 31) * 2, kc = tid >> 5;
            u16x8 lo, hi;
#pragma unroll
            for (int i = 0; i < 8; ++i) {
                int key = kc * 8 + i;
                unsigned t = 0;
                if (key < cnt) t = *(const unsigned*)(qkv + (size_t)(sbase + kt + key) * 2304 + 1536 + h * 64 + d);
                lo[i] = (u16)(t & 0xffffu); hi[i] = (u16)(t >> 16);
            }
            *(u16x8*)(Vt + d * 64 + ((kc ^ (d & 7)) << 3)) = lo;
            *(u16x8*)(Vt + (d + 1) * 64 + ((kc ^ ((d + 1) & 7)) << 3)) = hi;
        }
        __syncthreads();
        // ---- QK^T: S[2mb][4ni], C-layout row=query(quad*4+reg), col=key(l15+16ni) ----
        f32x4 acc_s[2][4] = {};
#pragma unroll
        for (int ni = 0; ni < 4; ++ni) {
            int key = l15 + ni * 16;
#pragma unroll
            for (int ks = 0; ks < 2; ++ks) {
                bf16x8 bk = *(const bf16x8*)(Ks + key * 64 + ((((ks << 2) + quad) ^ (key & 7)) << 3));
                acc_s[0][ni] = __builtin_amdgcn_mfma_f32_16x16x32_bf16(aq[0][ks], bk, acc_s[0][ni], 0, 0, 0);
                acc_s[1][ni] = __builtin_amdgcn_mfma_f32_16x16x32_bf16(aq[1][ks], bk, acc_s[1][ni], 0, 0, 0);
            }
        }
        // ---- online softmax per mb, write P (bf16) to per-wave LDS ----
#pragma unroll
        for (int mb = 0; mb < 2; ++mb) {
#pragma unroll
            for (int ni = 0; ni < 4; ++ni) {
                int keyabs = kt + l15 + ni * 16;
#pragma unroll
                for (int r = 0; r < 4; ++r) {
                    float sv = acc_s[mb][ni][r] * 0.125f;
                    if (keyabs >= kend) sv = -1e30f;
                    acc_s[mb][ni][r] = sv;
                }
            }
#pragma unroll
            for (int r = 0; r < 4; ++r) {
                float mx = fmaxf(fmaxf(acc_s[mb][0][r], acc_s[mb][1][r]), fmaxf(acc_s[mb][2][r], acc_s[mb][3][r]));
                mx = fmaxf(mx, __shfl_xor(mx, 1));
                mx = fmaxf(mx, __shfl_xor(mx, 2));
                mx = fmaxf(mx, __shfl_xor(mx, 4));
                mx = fmaxf(mx, __shfl_xor(mx, 8));
                float mnew = fmaxf(m_run[mb][r], mx);
                float pv[4], ps = 0.f;
#pragma unroll
                for (int ni = 0; ni < 4; ++ni) { pv[ni] = __expf(acc_s[mb][ni][r] - mnew); ps += pv[ni]; }
                ps += __shfl_xor(ps, 1);
                ps += __shfl_xor(ps, 2);
                ps += __shfl_xor(ps, 4);
                ps += __shfl_xor(ps, 8);
                float alpha = __expf(m_run[mb][r] - mnew);
                l_run[mb][r] = l_run[mb][r] * alpha + ps;
                m_run[mb][r] = mnew;
#pragma unroll
                for (int ni = 0; ni < 4; ++ni) acc_o[mb][ni][r] *= alpha;
                int prow = mb * 16 + quad * 4 + r;
#pragma unroll
                for (int ni = 0; ni < 4; ++ni) {
                    int key = l15 + ni * 16;
                    Pw[prow * 64 + (((key >> 3) ^ (prow & 7)) << 3) + (key & 7)] = f2bf(pv[ni]);
                }
            }
        }
        // ---- PV: A=P[m=query][k=key], B=Vt[k=key][n=dim] ----
        bf16x8 ap[2][2];
#pragma unroll
        for (int mb = 0; mb < 2; ++mb)
#pragma unroll
            for (int ks = 0; ks < 2; ++ks)
                ap[mb][ks] = *(const bf16x8*)(Pw + (mb * 16 + l15) * 64 + ((((ks << 2) + quad) ^ (l15 & 7)) << 3));
#pragma unroll
        for (int ni = 0; ni < 4; ++ni) {
            int d = l15 + ni * 16;
#pragma unroll
            for (int ks = 0; ks < 2; ++ks) {
                bf16x8 bv = *(const bf16x8*)(Vt + d * 64 + ((((ks << 2) + quad) ^ (d & 7)) << 3));
                acc_o[0][ni] = __builtin_amdgcn_mfma_f32_16x16x32_bf16(ap[0][ks], bv, acc_o[0][ni], 0, 0, 0);
                acc_o[1][ni] = __builtin_amdgcn_mfma_f32_16x16x32_bf16(ap[1][ks], bv, acc_o[1][ni], 0, 0, 0);
            }
        }
        __syncthreads();
    }
    // ---- write unnormalized O + (m,l) ----
    size_t gb = ((size_t)split * NG + g) * Sq;
#pragma unroll
    for (int mb = 0; mb < 2; ++mb)
#pragma unroll
        for (int r = 0; r < 4; ++r) {
            int q = q0w + mb * 16 + quad * 4 + r;
            if (q < Sq) {
                float* op = Ou + (gb + q) * 64;
#pragma unroll
                for (int ni = 0; ni < 4; ++ni) op[l15 + ni * 16] = acc_o[mb][ni][r];
                if (l15 == 0) {
                    ml[(gb + q) * 2]     = m_run[mb][r];
                    ml[(gb + q) * 2 + 1] = l_run[mb][r];
                }
            }
        }
}

// ---------------- combine splits (+vmean for even layers) -> ob bf16 ----------------
__global__ __launch_bounds__(256) void comb_k(const float* __restrict__ Ou, const float* __restrict__ ml,
                                              const float* __restrict__ vm, u16* __restrict__ ob,
                                              int even, int nsplit, int NG, int Sq) {
    int g = blockIdx.y;
    int q = blockIdx.x * 4 + (threadIdx.x >> 6);
    int d = threadIdx.x & 63;
    if (q >= Sq) return;
    int h, sbase;
    if (even) { h = g >> 3; sbase = (g & 7) * Nn; } else { h = g; sbase = 0; }
    float M = -INFINITY;
    for (int s = 0; s < nsplit; ++s) M = fmaxf(M, ml[(((size_t)s * NG + g) * Sq + q) * 2]);
    float num = 0.f, den = 0.f;
    for (int s = 0; s < nsplit; ++s) {
        size_t base = ((size_t)s * NG + g) * Sq + q;
        float wgt = __expf(ml[base * 2] - M);
        den += wgt * ml[base * 2 + 1];
        num += wgt * Ou[base * 64 + d];
    }
    float o = num / den;
    if (even) o += vm[g * 64 + d];
    ob[(size_t)(sbase + q) * Dm + h * 64 + d] = f2bf(o);
}

extern "C" void kernel_launch(void* const* d_in, const int* in_sizes, int n_in,
                              void* d_out, int out_size, void* d_ws, size_t ws_size,
                              hipStream_t stream) {
    (void)in_sizes; (void)n_in; (void)out_size; (void)ws_size;
    const float* x       = (const float*)d_in[0];
    const float* W_patch = (const float*)d_in[1];
    const float* b_patch = (const float*)d_in[2];
    const float* cls     = (const float*)d_in[3];
    const float* pos     = (const float*)d_in[4];
    const float* ln1_g   = (const float*)d_in[5];
    const float* ln1_b   = (const float*)d_in[6];
    const float* qkv_w   = (const float*)d_in[7];
    const float* qkv_b   = (const float*)d_in[8];
    const float* proj_w  = (const float*)d_in[9];
    const float* proj_b  = (const float*)d_in[10];
    const float* ln2_g   = (const float*)d_in[11];
    const float* ln2_b   = (const float*)d_in[12];
    const float* fc1_w   = (const float*)d_in[13];
    const float* fc1_b   = (const float*)d_in[14];
    const float* fc2_w   = (const float*)d_in[15];
    const float* fc2_b   = (const float*)d_in[16];
    const float* lnf_g   = (const float*)d_in[17];
    const float* lnf_b   = (const float*)d_in[18];

    char* base = (char*)d_ws;
    auto alloc = [&](size_t bytes) { void* p = base; base += (bytes + 255) & ~(size_t)255; return p; };
    u16*   P    = (u16*)  alloc((size_t)MPAD * 768 * 2);
    u16*   Wq   = (u16*)  alloc((size_t)2304 * 768 * 2);
    u16*   Wp   = (u16*)  alloc((size_t)768 * 768 * 2);
    u16*   W1   = (u16*)  alloc((size_t)3072 * 768 * 2);
    u16*   W2   = (u16*)  alloc((size_t)768 * 3072 * 2);
    float* emb  = (float*)alloc((size_t)1568 * 768 * 4);
    float* h    = (float*)alloc((size_t)Sn * Dm * 4);
    u16*   a    = (u16*)  alloc((size_t)MPAD * 768 * 2);
    u16*   qkvb = (u16*)  alloc((size_t)Sn * 2304 * 2);
    u16*   ob   = (u16*)  alloc((size_t)MPAD * 768 * 2);
    u16*   mb   = (u16*)  alloc((size_t)MPAD * 3072 * 2);
    float* vm   = (float*)alloc((size_t)96 * 64 * 4);
    float* Ou   = (float*)alloc((size_t)3 * 12 * Sn * 64 * 4);
    float* ml   = (float*)alloc((size_t)3 * 12 * Sn * 2 * 4);
    float* Cp   = (float*)alloc((size_t)3 * MPAD * 2304 * 4);   // max over all gemms

    // ---- patch embed ----
    im2col_k<<<(1568 * 768 + 255) / 256, 256, 0, stream>>>(x, P);
    cvt_k<<<(768 * 768 + 255) / 256, 256, 0, stream>>>(W_patch, Wp, 768 * 768);
    mgemm_k<<<dim3(6, 13, 3), 256, 0, stream>>>(P, Wp, Cp, 768, 768, 256);
    ep_k<false, false, float><<<dim3(1, 1568), 256, 0, stream>>>(Cp, b_patch, nullptr, emb, 768, 3);
    build_h_k<<<(Sn * Dm + 255) / 256, 256, 0, stream>>>(emb, cls, pos, h);

    for (int i = 0; i < 12; ++i) {
        cvtT_layer_k<<<6912, 256, 0, stream>>>(
            qkv_w + (size_t)i * 768 * 2304, proj_w + (size_t)i * 768 * 768,
            fc1_w + (size_t)i * 768 * 3072, fc2_w + (size_t)i * 3072 * 768,
            Wq, Wp, W1, W2);
        ln_k<u16><<<Sn, 256, 0, stream>>>(h, ln1_g + i * Dm, ln1_b + i * Dm, a);
        mgemm_k<<<dim3(18, 13, 3), 256, 0, stream>>>(a, Wq, Cp, 2304, 768, 256);
        ep_k<false, false, u16><<<dim3(3, Sn), 256, 0, stream>>>(Cp, qkv_b + i * 2304, nullptr, qkvb, 2304, 3);
        if ((i & 1) == 0) {
            vmean_k<<<96, 64, 0, stream>>>(qkvb, vm);
            attn_mfma_k<<<dim3(2, 96, 1), 256, 0, stream>>>(qkvb, Ou, ml, 1, 1, 96, Nn);
            comb_k<<<dim3(50, 96), 256, 0, stream>>>(Ou, ml, vm, ob, 1, 1, 96, Nn);
        } else {
            attn_mfma_k<<<dim3(13, 12, 3), 256, 0, stream>>>(qkvb, Ou, ml, 0, 3, 12, Sn);
            comb_k<<<dim3(394, 12), 256, 0, stream>>>(Ou, ml, vm, ob, 0, 3, 12, Sn);
        }
        mgemm_k<<<dim3(6, 13, 4), 256, 0, stream>>>(ob, Wp, Cp, 768, 768, 192);
        ep_k<false, true, float><<<dim3(1, Sn), 256, 0, stream>>>(Cp, proj_b + i * Dm, h, h, 768, 4);
        ln_k<u16><<<Sn, 256, 0, stream>>>(h, ln2_g + i * Dm, ln2_b + i * Dm, a);
        mgemm_k<<<dim3(24, 13, 2), 256, 0, stream>>>(a, W1, Cp, 3072, 768, 384);
        ep_k<true, false, u16><<<dim3(3, Sn), 256, 0, stream>>>(Cp, fc1_b + i * MLPn, nullptr, mb, 3072, 2);
        mgemm_k<<<dim3(6, 13, 4), 256, 0, stream>>>(mb, W2, Cp, 768, 3072, 768);
        ep_k<false, true, float><<<dim3(1, Sn), 256, 0, stream>>>(Cp, fc2_b + i * Dm, h, h, 768, 4);
    }
    ln_k<float><<<Sn, 256, 0, stream>>>(h, lnf_g, lnf_b, (float*)d_out);
}

// Round 2
// 2369.270 us; speedup vs baseline: 1.0340x; 1.0340x over previous
//
#include <hip/hip_runtime.h>
#include <math.h>

#define Dm 768
#define Tn 8
#define Nn 197
#define Sn 1576
#define MLPn 3072
#define NPn 196
#define MPAD 1664   // 13*128 = 26*64

typedef unsigned short u16;
typedef __bf16 bf16x8 __attribute__((ext_vector_type(8)));
typedef float f32x4 __attribute__((ext_vector_type(4)));
typedef unsigned int u32x4 __attribute__((ext_vector_type(4)));
typedef u16 u16x8 __attribute__((ext_vector_type(8)));
typedef u16 u16x4 __attribute__((ext_vector_type(4)));

__device__ inline u16 f2bf(float f) {
    union { float f; unsigned u; } v; v.f = f;
    unsigned r = v.u + 0x7fffu + ((v.u >> 16) & 1u);
    return (u16)(r >> 16);
}
__device__ inline float bf2f(u16 v) {
    union { unsigned u; float f; } x; x.u = ((unsigned)v) << 16; return x.f;
}

// async global->LDS, 16B per lane. LDS dest is wave-uniform base + lane*16.
__device__ __forceinline__ void gl_lds16(const u16* __restrict__ g, u16* l) {
    __builtin_amdgcn_global_load_lds((const __attribute__((address_space(1))) void*)g,
                                     (__attribute__((address_space(3))) void*)l,
                                     16, 0, 0);
}

// ---------------- im2col: x[1,8,3,224,224] -> P[1568,768] bf16 ----------------
__global__ __launch_bounds__(256) void im2col_k(const float* __restrict__ x, u16* __restrict__ P) {
    int idx = blockIdx.x * 256 + threadIdx.x;
    if (idx >= 1568 * 768) return;
    int c = idx % 768, r = idx / 768;
    int p = r % 196, t = r / 196;
    int hp = p / 14, wp = p % 14;
    int ch = c / 256, rem = c % 256, py = rem / 16, px = rem % 16;
    P[idx] = f2bf(x[((t * 3 + ch) * 224 + hp * 16 + py) * 224 + wp * 16 + px]);
}

__global__ __launch_bounds__(256) void cvt_k(const float* __restrict__ s, u16* __restrict__ d, int n) {
    int i = blockIdx.x * 256 + threadIdx.x;
    if (i < n) d[i] = f2bf(s[i]);
}

// ---------------- per-layer weight transpose+convert: fp32 [K,N] -> bf16 [N,K] ----------------
__global__ __launch_bounds__(256) void cvtT_layer_k(const float* __restrict__ qw, const float* __restrict__ pw,
                                                    const float* __restrict__ f1w, const float* __restrict__ f2w,
                                                    u16* __restrict__ Wq, u16* __restrict__ Wp,
                                                    u16* __restrict__ W1, u16* __restrict__ W2) {
    __shared__ float tile[32][33];
    int bid = blockIdx.x;
    const float* src; u16* dst; int K, N, k0, n0;
    if (bid < 1728)      { src = qw;  dst = Wq; K = 768;  N = 2304; int r = bid;        k0 = (r / 72) * 32; n0 = (r % 72) * 32; }
    else if (bid < 2304) { src = pw;  dst = Wp; K = 768;  N = 768;  int r = bid - 1728; k0 = (r / 24) * 32; n0 = (r % 24) * 32; }
    else if (bid < 4608) { src = f1w; dst = W1; K = 768;  N = 3072; int r = bid - 2304; k0 = (r / 96) * 32; n0 = (r % 96) * 32; }
    else                 { src = f2w; dst = W2; K = 3072; N = 768;  int r = bid - 4608; k0 = (r / 24) * 32; n0 = (r % 24) * 32; }
    int tx = threadIdx.x & 31, ty = threadIdx.x >> 5;
#pragma unroll
    for (int i = 0; i < 4; ++i) tile[ty + 8 * i][tx] = src[(size_t)(k0 + ty + 8 * i) * N + n0 + tx];
    __syncthreads();
#pragma unroll
    for (int i = 0; i < 4; ++i) dst[(size_t)(n0 + ty + 8 * i) * K + k0 + tx] = f2bf(tile[tx][ty + 8 * i]);
}

// ---------------- scramble + cls + pos -> h[1576,768] fp32 ----------------
__global__ __launch_bounds__(256) void build_h_k(const float* __restrict__ emb, const float* __restrict__ cls,
                                                 const float* __restrict__ pos, float* __restrict__ h) {
    int idx = blockIdx.x * 256 + threadIdx.x;
    if (idx >= Sn * Dm) return;
    int d = idx % Dm, s = idx / Dm;
    int t = s / Nn, r = s % Nn;
    float v;
    if (r == 0) v = cls[d];
    else {
        int f = (r - 1) * Dm + d;
        int p = f % NPn, dd = f / NPn;
        v = emb[(size_t)(t * NPn + p) * Dm + dd];
    }
    h[idx] = v + pos[r * Dm + d];
}

// ---------------- LayerNorm (standalone; used once after build_h) ----------------
template <typename OutT>
__global__ __launch_bounds__(256) void ln_k(const float* __restrict__ X, const float* __restrict__ g,
                                            const float* __restrict__ bta, OutT* __restrict__ Y) {
    int row = blockIdx.x;
    const float* x = X + (size_t)row * Dm;
    float s = 0.f, s2 = 0.f;
#pragma unroll
    for (int q = 0; q < 3; ++q) {
        float v = x[threadIdx.x + q * 256];
        s += v; s2 += v * v;
    }
#pragma unroll
    for (int off = 1; off < 64; off <<= 1) {
        s  += __shfl_xor(s,  off);
        s2 += __shfl_xor(s2, off);
    }
    __shared__ float red[8];
    int wv = threadIdx.x >> 6;
    if ((threadIdx.x & 63) == 0) { red[wv * 2] = s; red[wv * 2 + 1] = s2; }
    __syncthreads();
    s  = red[0] + red[2] + red[4] + red[6];
    s2 = red[1] + red[3] + red[5] + red[7];
    float mu  = s * (1.f / 768.f);
    float var = s2 * (1.f / 768.f) - mu * mu;
    float rstd = rsqrtf(var + 1e-5f);
#pragma unroll
    for (int q = 0; q < 3; ++q) {
        int i = threadIdx.x + q * 256;
        float v = (x[i] - mu) * rstd * g[i] + bta[i];
        if constexpr (sizeof(OutT) == 2) Y[(size_t)row * Dm + i] = f2bf(v);
        else                             Y[(size_t)row * Dm + i] = v;
    }
}

// ---------------- split-K MFMA GEMM (proj / fc2 / patch): Cp[split][MPAD][N] ----------------
__global__ __launch_bounds__(256) void mgemm_k(const u16* __restrict__ A, const u16* __restrict__ Bt,
                                               float* __restrict__ Cp, int N, int Kfull, int Kc) {
    __shared__ __align__(16) u16 As[4096];
    __shared__ __align__(16) u16 Bs[4096];
    int split = blockIdx.z;
    A  += split * Kc;
    Bt += split * Kc;
    Cp += (size_t)split * MPAD * N;
    int tid = threadIdx.x;
    int lane = tid & 63, w = tid >> 6;
    int wm = w & 1, wn = w >> 1;
    int m0 = blockIdx.y * 128, n0 = blockIdx.x * 128;
    f32x4 acc[4][4] = {};
    int c0 = tid, c1 = tid + 256;
    int ar0 = ((c0 >> 6) << 4) + (c0 & 15), ac0 = ((c0 >> 4) & 3) << 3;
    int ar1 = ((c1 >> 6) << 4) + (c1 & 15), ac1 = ((c1 >> 4) & 3) << 3;
    const u16* Arow0 = A  + (size_t)(m0 + ar0) * Kfull + ac0;
    const u16* Arow1 = A  + (size_t)(m0 + ar1) * Kfull + ac1;
    const u16* Brow0 = Bt + (size_t)(n0 + ar0) * Kfull + ac0;
    const u16* Brow1 = Bt + (size_t)(n0 + ar1) * Kfull + ac1;
    u16* As0 = As + (w * 64) * 8;
    u16* As1 = As + (256 + w * 64) * 8;
    u16* Bs0 = Bs + (w * 64) * 8;
    u16* Bs1 = Bs + (256 + w * 64) * 8;
    for (int k0 = 0; k0 < Kc; k0 += 32) {
        gl_lds16(Arow0 + k0, As0);
        gl_lds16(Arow1 + k0, As1);
        gl_lds16(Brow0 + k0, Bs0);
        gl_lds16(Brow1 + k0, Bs1);
        __syncthreads();
        bf16x8 af[4], bfr[4];
#pragma unroll
        for (int i = 0; i < 4; ++i) {
            af[i]  = *(const bf16x8*)(As + (((wm * 4 + i) * 64 + lane) << 3));
            bfr[i] = *(const bf16x8*)(Bs + (((wn * 4 + i) * 64 + lane) << 3));
        }
#pragma unroll
        for (int mi = 0; mi < 4; ++mi)
#pragma unroll
            for (int ni = 0; ni < 4; ++ni)
                acc[mi][ni] = __builtin_amdgcn_mfma_f32_16x16x32_bf16(af[mi], bfr[ni], acc[mi][ni], 0, 0, 0);
        __syncthreads();
    }
    int rbase = (lane >> 4) << 2, cl = lane & 15;
#pragma unroll
    for (int mi = 0; mi < 4; ++mi)
#pragma unroll
        for (int r = 0; r < 4; ++r) {
            int gm = m0 + wm * 64 + mi * 16 + rbase + r;
#pragma unroll
            for (int ni = 0; ni < 4; ++ni) {
                int gn = n0 + wn * 64 + ni * 16 + cl;
                Cp[(size_t)gm * N + gn] = acc[mi][ni][r];
            }
        }
}

// ---------------- fused no-split GEMM (qkv / fc1): 64x128 tile, bias[+gelu] -> bf16 ----------------
// 4 waves as 2(m)x2(n); per wave 32x64 = 2x4 fragments. K-loop over full K.
template <bool GELU_ACT>
__global__ __launch_bounds__(256) void mgemm_fused_k(const u16* __restrict__ A, const u16* __restrict__ Bt,
                                                     const float* __restrict__ bias, u16* __restrict__ out,
                                                     int N, int Kfull, int Mout) {
    __shared__ __align__(16) u16 As[64 * 32];    // 4 KB
    __shared__ __align__(16) u16 Bs[128 * 32];   // 8 KB
    int tid = threadIdx.x;
    int lane = tid & 63, w = tid >> 6;
    int wm = w & 1, wn = w >> 1;
    int m0 = blockIdx.y * 64, n0 = blockIdx.x * 128;
    f32x4 acc[2][4] = {};
    // A: 256 chunks (64 rows x 4 kchunks), one per thread
    int ca = tid;
    int ar = ((ca >> 6) << 4) + (ca & 15), ac = ((ca >> 4) & 3) << 3;
    const u16* Arow = A + (size_t)(m0 + ar) * Kfull + ac;
    // B: 512 chunks (128 rows x 4 kchunks), two per thread
    int cb1 = tid + 256;
    int br1 = ((cb1 >> 6) << 4) + (cb1 & 15), bc1 = ((cb1 >> 4) & 3) << 3;
    const u16* Brow0 = Bt + (size_t)(n0 + ar) * Kfull + ac;     // chunk tid: same row/col formula
    const u16* Brow1 = Bt + (size_t)(n0 + br1) * Kfull + bc1;
    u16* Asw  = As + (w * 64) * 8;
    u16* Bsw0 = Bs + (w * 64) * 8;
    u16* Bsw1 = Bs + (256 + w * 64) * 8;
    for (int k0 = 0; k0 < Kfull; k0 += 32) {
        gl_lds16(Arow + k0, Asw);
        gl_lds16(Brow0 + k0, Bsw0);
        gl_lds16(Brow1 + k0, Bsw1);
        __syncthreads();
        bf16x8 af[2], bfr[4];
#pragma unroll
        for (int i = 0; i < 2; ++i) af[i]  = *(const bf16x8*)(As + (((wm * 2 + i) * 64 + lane) << 3));
#pragma unroll
        for (int j = 0; j < 4; ++j) bfr[j] = *(const bf16x8*)(Bs + (((wn * 4 + j) * 64 + lane) << 3));
#pragma unroll
        for (int mi = 0; mi < 2; ++mi)
#pragma unroll
            for (int ni = 0; ni < 4; ++ni)
                acc[mi][ni] = __builtin_amdgcn_mfma_f32_16x16x32_bf16(af[mi], bfr[ni], acc[mi][ni], 0, 0, 0);
        __syncthreads();
    }
    int rbase = (lane >> 4) << 2, cl = lane & 15;
#pragma unroll
    for (int mi = 0; mi < 2; ++mi)
#pragma unroll
        for (int r = 0; r < 4; ++r) {
            int gm = m0 + wm * 32 + mi * 16 + rbase + r;
            if (gm < Mout) {
#pragma unroll
                for (int ni = 0; ni < 4; ++ni) {
                    int gn = n0 + wn * 64 + ni * 16 + cl;
                    float v = acc[mi][ni][r] + bias[gn];
                    if (GELU_ACT) v = 0.5f * v * (1.f + erff(v * 0.7071067811865476f));
                    out[(size_t)gm * N + gn] = f2bf(v);
                }
            }
        }
}

// ---------------- epilogue (patch embed only): sum splits + bias -> fp32 ----------------
__global__ __launch_bounds__(256) void ep_k(const float* __restrict__ Cp, const float* __restrict__ bias,
                                            float* __restrict__ out, int N, int S) {
    int row = blockIdx.y;
    int n = blockIdx.x * 1024 + threadIdx.x * 4;
    if (n >= N) return;
    size_t off = (size_t)row * N + n;
    f32x4 acc = *(const f32x4*)(Cp + off);
    for (int s = 1; s < S; ++s)
        acc += *(const f32x4*)(Cp + (size_t)s * MPAD * N + off);
    acc += *(const f32x4*)(bias + n);
    *(f32x4*)(out + off) = acc;
}

// ---------------- fused epilogue (proj / fc2): sum splits + bias + resid -> h, then LN -> lnout ----------------
template <bool FINALOUT>
__global__ __launch_bounds__(256) void ep_ln_k(const float* __restrict__ Cp, const float* __restrict__ bias,
                                               float* __restrict__ h, const float* __restrict__ g,
                                               const float* __restrict__ bta, void* __restrict__ lnout, int S) {
    int row = blockIdx.x;
    int t = threadIdx.x;
    float v[3];
    float s = 0.f, s2 = 0.f;
#pragma unroll
    for (int q = 0; q < 3; ++q) {
        int i = t + q * 256;
        size_t off = (size_t)row * Dm + i;
        float a = Cp[off];
        for (int sp = 1; sp < S; ++sp) a += Cp[(size_t)sp * MPAD * Dm + off];
        a += bias[i] + h[off];
        h[off] = a;
        v[q] = a; s += a; s2 += a * a;
    }
#pragma unroll
    for (int off = 1; off < 64; off <<= 1) {
        s  += __shfl_xor(s,  off);
        s2 += __shfl_xor(s2, off);
    }
    __shared__ float red[8];
    int wv = t >> 6;
    if ((t & 63) == 0) { red[wv * 2] = s; red[wv * 2 + 1] = s2; }
    __syncthreads();
    s  = red[0] + red[2] + red[4] + red[6];
    s2 = red[1] + red[3] + red[5] + red[7];
    float mu  = s * (1.f / 768.f);
    float var = s2 * (1.f / 768.f) - mu * mu;
    float rstd = rsqrtf(var + 1e-5f);
#pragma unroll
    for (int q = 0; q < 3; ++q) {
        int i = t + q * 256;
        float y = (v[q] - mu) * rstd * g[i] + bta[i];
        if constexpr (FINALOUT) ((float*)lnout)[(size_t)row * Dm + i] = y;
        else                    ((u16*)lnout)[(size_t)row * Dm + i] = f2bf(y);
    }
}

// ---------------- per-(head,frame) mean of V (bf16 input) ----------------
__global__ __launch_bounds__(64) void vmean_k(const u16* __restrict__ qkv, float* __restrict__ vm) {
    int g = blockIdx.x;      // g = h*8 + t
    int h = g >> 3, t = g & 7;
    int d = threadIdx.x;
    float s = 0.f;
    for (int n = 0; n < Nn; ++n)
        s += bf2f(qkv[(size_t)(t * Nn + n) * 2304 + 1536 + h * 64 + d]);
    vm[g * 64 + d] = s * (1.f / 197.f);
}

// ---------------- MFMA flash attention ----------------
__global__ __launch_bounds__(256) void attn_mfma_k(const u16* __restrict__ qkv, float* __restrict__ Ou,
                                                   float* __restrict__ ml, int even, int nsplit,
                                                   int NG, int Sq) {
    __shared__ __align__(16) u16 Ks[64 * 64];
    __shared__ __align__(16) u16 Vt[64 * 64];
    __shared__ __align__(16) u16 Ps[4 * 32 * 64];
    int g = blockIdx.y;
    int h, sbase;
    if (even) { h = g >> 3; sbase = (g & 7) * Nn; } else { h = g; sbase = 0; }
    int split = blockIdx.z;
    int chunk = (Sq + nsplit - 1) / nsplit;
    int kbeg = split * chunk, kend = min(Sq, kbeg + chunk);
    int tid = threadIdx.x, lane = tid & 63, w = tid >> 6;
    int quad = lane >> 4, l15 = lane & 15;
    int q0w = blockIdx.x * 128 + w * 32;
    u16* Pw = Ps + w * 2048;

    bf16x8 aq[2][2];
#pragma unroll
    for (int mb = 0; mb < 2; ++mb) {
        int qidx = q0w + mb * 16 + l15; if (qidx >= Sq) qidx = Sq - 1;
        const u16* qp = qkv + (size_t)(sbase + qidx) * 2304 + h * 64;
#pragma unroll
        for (int ks = 0; ks < 2; ++ks)
            aq[mb][ks] = *(const bf16x8*)(qp + ks * 32 + quad * 8);
    }
    f32x4 acc_o[2][4] = {};
    float m_run[2][4], l_run[2][4];
#pragma unroll
    for (int mb = 0; mb < 2; ++mb)
#pragma unroll
        for (int r = 0; r < 4; ++r) { m_run[mb][r] = -INFINITY; l_run[mb][r] = 0.f; }

    for (int kt = kbeg; kt < kend; kt += 64) {
        int cnt = kend - kt; if (cnt > 64) cnt = 64;
        {
            int dc = tid & 7;
#pragma unroll
            for (int p = 0; p < 2; ++p) {
                int row = (tid >> 3) + 32 * p;
                u32x4 kd = {};
                if (row < cnt) kd = *(const u32x4*)(qkv + (size_t)(sbase + kt + row) * 2304 + 768 + h * 64 + dc * 8);
                *(u32x4*)(Ks + row * 64 + ((dc ^ (row & 7)) << 3)) = kd;
            }
        }
        {
            int d = (tid & 31) * 2, kc = tid >> 5;
            u16x8 lo, hi;
#pragma unroll
            for (int i = 0; i < 8; ++i) {
                int key = kc * 8 + i;
                unsigned t = 0;
                if (key < cnt) t = *(const unsigned*)(qkv + (size_t)(sbase + kt + key) * 2304 + 1536 + h * 64 + d);
                lo[i] = (u16)(t & 0xffffu); hi[i] = (u16)(t >> 16);
            }
            *(u16x8*)(Vt + d * 64 + ((kc ^ (d & 7)) << 3)) = lo;
            *(u16x8*)(Vt + (d + 1) * 64 + ((kc ^ ((d + 1) & 7)) << 3)) = hi;
        }
        __syncthreads();
        f32x4 acc_s[2][4] = {};
#pragma unroll
        for (int ni = 0; ni < 4; ++ni) {
            int key = l15 + ni * 16;
#pragma unroll
            for (int ks = 0; ks < 2; ++ks) {
                bf16x8 bk = *(const bf16x8*)(Ks + key * 64 + ((((ks << 2) + quad) ^ (key & 7)) << 3));
                acc_s[0][ni] = __builtin_amdgcn_mfma_f32_16x16x32_bf16(aq[0][ks], bk, acc_s[0][ni], 0, 0, 0);
                acc_s[1][ni] = __builtin_amdgcn_mfma_f32_16x16x32_bf16(aq[1][ks], bk, acc_s[1][ni], 0, 0, 0);
            }
        }
#pragma unroll
        for (int mb = 0; mb < 2; ++mb) {
#pragma unroll
            for (int ni = 0; ni < 4; ++ni) {
                int keyabs = kt + l15 + ni * 16;
#pragma unroll
                for (int r = 0; r < 4; ++r) {
                    float sv = acc_s[mb][ni][r] * 0.125f;
                    if (keyabs >= kend) sv = -1e30f;
                    acc_s[mb][ni][r] = sv;
                }
            }
#pragma unroll
            for (int r = 0; r < 4; ++r) {
                float mx = fmaxf(fmaxf(acc_s[mb][0][r], acc_s[mb][1][r]), fmaxf(acc_s[mb][2][r], acc_s[mb][3][r]));
                mx = fmaxf(mx, __shfl_xor(mx, 1));
                mx = fmaxf(mx, __shfl_xor(mx, 2));
                mx = fmaxf(mx, __shfl_xor(mx, 4));
                mx = fmaxf(mx, __shfl_xor(mx, 8));
                float mnew = fmaxf(m_run[mb][r], mx);
                float pv[4], ps = 0.f;
#pragma unroll
                for (int ni = 0; ni < 4; ++ni) { pv[ni] = __expf(acc_s[mb][ni][r] - mnew); ps += pv[ni]; }
                ps += __shfl_xor(ps, 1);
                ps += __shfl_xor(ps, 2);
                ps += __shfl_xor(ps, 4);
                ps += __shfl_xor(ps, 8);
                float alpha = __expf(m_run[mb][r] - mnew);
                l_run[mb][r] = l_run[mb][r] * alpha + ps;
                m_run[mb][r] = mnew;
#pragma unroll
                for (int ni = 0; ni < 4; ++ni) acc_o[mb][ni][r] *= alpha;
                int prow = mb * 16 + quad * 4 + r;
#pragma unroll
                for (int ni = 0; ni < 4; ++ni) {
                    int key = l15 + ni * 16;
                    Pw[prow * 64 + (((key >> 3) ^ (prow & 7)) << 3) + (key & 7)] = f2bf(pv[ni]);
                }
            }
        }
        bf16x8 ap[2][2];
#pragma unroll
        for (int mb = 0; mb < 2; ++mb)
#pragma unroll
            for (int ks = 0; ks < 2; ++ks)
                ap[mb][ks] = *(const bf16x8*)(Pw + (mb * 16 + l15) * 64 + ((((ks << 2) + quad) ^ (l15 & 7)) << 3));
#pragma unroll
        for (int ni = 0; ni < 4; ++ni) {
            int d = l15 + ni * 16;
#pragma unroll
            for (int ks = 0; ks < 2; ++ks) {
                bf16x8 bv = *(const bf16x8*)(Vt + d * 64 + ((((ks << 2) + quad) ^ (d & 7)) << 3));
                acc_o[0][ni] = __builtin_amdgcn_mfma_f32_16x16x32_bf16(ap[0][ks], bv, acc_o[0][ni], 0, 0, 0);
                acc_o[1][ni] = __builtin_amdgcn_mfma_f32_16x16x32_bf16(ap[1][ks], bv, acc_o[1][ni], 0, 0, 0);
            }
        }
        __syncthreads();
    }
    size_t gb = ((size_t)split * NG + g) * Sq;
#pragma unroll
    for (int mb = 0; mb < 2; ++mb)
#pragma unroll
        for (int r = 0; r < 4; ++r) {
            int q = q0w + mb * 16 + quad * 4 + r;
            if (q < Sq) {
                float* op = Ou + (gb + q) * 64;
#pragma unroll
                for (int ni = 0; ni < 4; ++ni) op[l15 + ni * 16] = acc_o[mb][ni][r];
                if (l15 == 0) {
                    ml[(gb + q) * 2]     = m_run[mb][r];
                    ml[(gb + q) * 2 + 1] = l_run[mb][r];
                }
            }
        }
}

// ---------------- combine splits (+vmean for even layers) -> ob bf16 ----------------
__global__ __launch_bounds__(256) void comb_k(const float* __restrict__ Ou, const float* __restrict__ ml,
                                              const float* __restrict__ vm, u16* __restrict__ ob,
                                              int even, int nsplit, int NG, int Sq) {
    int g = blockIdx.y;
    int q = blockIdx.x * 4 + (threadIdx.x >> 6);
    int d = threadIdx.x & 63;
    if (q >= Sq) return;
    int h, sbase;
    if (even) { h = g >> 3; sbase = (g & 7) * Nn; } else { h = g; sbase = 0; }
    float M = -INFINITY;
    for (int s = 0; s < nsplit; ++s) M = fmaxf(M, ml[(((size_t)s * NG + g) * Sq + q) * 2]);
    float num = 0.f, den = 0.f;
    for (int s = 0; s < nsplit; ++s) {
        size_t base = ((size_t)s * NG + g) * Sq + q;
        float wgt = __expf(ml[base * 2] - M);
        den += wgt * ml[base * 2 + 1];
        num += wgt * Ou[base * 64 + d];
    }
    float o = num / den;
    if (even) o += vm[g * 64 + d];
    ob[(size_t)(sbase + q) * Dm + h * 64 + d] = f2bf(o);
}

extern "C" void kernel_launch(void* const* d_in, const int* in_sizes, int n_in,
                              void* d_out, int out_size, void* d_ws, size_t ws_size,
                              hipStream_t stream) {
    (void)in_sizes; (void)n_in; (void)out_size; (void)ws_size;
    const float* x       = (const float*)d_in[0];
    const float* W_patch = (const float*)d_in[1];
    const float* b_patch = (const float*)d_in[2];
    const float* cls     = (const float*)d_in[3];
    const float* pos     = (const float*)d_in[4];
    const float* ln1_g   = (const float*)d_in[5];
    const float* ln1_b   = (const float*)d_in[6];
    const float* qkv_w   = (const float*)d_in[7];
    const float* qkv_b   = (const float*)d_in[8];
    const float* proj_w  = (const float*)d_in[9];
    const float* proj_b  = (const float*)d_in[10];
    const float* ln2_g   = (const float*)d_in[11];
    const float* ln2_b   = (const float*)d_in[12];
    const float* fc1_w   = (const float*)d_in[13];
    const float* fc1_b   = (const float*)d_in[14];
    const float* fc2_w   = (const float*)d_in[15];
    const float* fc2_b   = (const float*)d_in[16];
    const float* lnf_g   = (const float*)d_in[17];
    const float* lnf_b   = (const float*)d_in[18];

    char* base = (char*)d_ws;
    auto alloc = [&](size_t bytes) { void* p = base; base += (bytes + 255) & ~(size_t)255; return p; };
    u16*   P    = (u16*)  alloc((size_t)MPAD * 768 * 2);
    u16*   Wq   = (u16*)  alloc((size_t)2304 * 768 * 2);
    u16*   Wp   = (u16*)  alloc((size_t)768 * 768 * 2);
    u16*   W1   = (u16*)  alloc((size_t)3072 * 768 * 2);
    u16*   W2   = (u16*)  alloc((size_t)768 * 3072 * 2);
    float* emb  = (float*)alloc((size_t)1568 * 768 * 4);
    float* h    = (float*)alloc((size_t)Sn * Dm * 4);
    u16*   a    = (u16*)  alloc((size_t)MPAD * 768 * 2);
    u16*   qkvb = (u16*)  alloc((size_t)Sn * 2304 * 2);
    u16*   ob   = (u16*)  alloc((size_t)MPAD * 768 * 2);
    u16*   mb   = (u16*)  alloc((size_t)MPAD * 3072 * 2);
    float* vm   = (float*)alloc((size_t)96 * 64 * 4);
    float* Ou   = (float*)alloc((size_t)3 * 12 * Sn * 64 * 4);
    float* ml   = (float*)alloc((size_t)3 * 12 * Sn * 2 * 4);
    float* Cp   = (float*)alloc((size_t)4 * MPAD * 768 * 4);   // split-K partials (proj/fc2/patch)

    // ---- patch embed ----
    im2col_k<<<(1568 * 768 + 255) / 256, 256, 0, stream>>>(x, P);
    cvt_k<<<(768 * 768 + 255) / 256, 256, 0, stream>>>(W_patch, Wp, 768 * 768);
    mgemm_k<<<dim3(6, 13, 3), 256, 0, stream>>>(P, Wp, Cp, 768, 768, 256);
    ep_k<<<dim3(1, 1568), 256, 0, stream>>>(Cp, b_patch, emb, 768, 3);
    build_h_k<<<(Sn * Dm + 255) / 256, 256, 0, stream>>>(emb, cls, pos, h);
    ln_k<u16><<<Sn, 256, 0, stream>>>(h, ln1_g, ln1_b, a);   // layer-0 ln1

    for (int i = 0; i < 12; ++i) {
        cvtT_layer_k<<<6912, 256, 0, stream>>>(
            qkv_w + (size_t)i * 768 * 2304, proj_w + (size_t)i * 768 * 768,
            fc1_w + (size_t)i * 768 * 3072, fc2_w + (size_t)i * 3072 * 768,
            Wq, Wp, W1, W2);
        // qkv: fused no-split GEMM, bias -> bf16
        mgemm_fused_k<false><<<dim3(18, 26), 256, 0, stream>>>(a, Wq, qkv_b + i * 2304, qkvb, 2304, 768, Sn);
        if ((i & 1) == 0) {
            vmean_k<<<96, 64, 0, stream>>>(qkvb, vm);
            attn_mfma_k<<<dim3(2, 96, 1), 256, 0, stream>>>(qkvb, Ou, ml, 1, 1, 96, Nn);
            comb_k<<<dim3(50, 96), 256, 0, stream>>>(Ou, ml, vm, ob, 1, 1, 96, Nn);
        } else {
            attn_mfma_k<<<dim3(13, 12, 3), 256, 0, stream>>>(qkvb, Ou, ml, 0, 3, 12, Sn);
            comb_k<<<dim3(394, 12), 256, 0, stream>>>(Ou, ml, vm, ob, 0, 3, 12, Sn);
        }
        // proj: split-K GEMM + fused (bias+resid -> h, ln2 -> a)
        mgemm_k<<<dim3(6, 13, 4), 256, 0, stream>>>(ob, Wp, Cp, 768, 768, 192);
        ep_ln_k<false><<<Sn, 256, 0, stream>>>(Cp, proj_b + i * Dm, h, ln2_g + i * Dm, ln2_b + i * Dm, a, 4);
        // fc1: fused no-split GEMM, bias+gelu -> bf16
        mgemm_fused_k<true><<<dim3(24, 26), 256, 0, stream>>>(a, W1, fc1_b + i * MLPn, mb, 3072, 768, Sn);
        // fc2: split-K GEMM + fused (bias+resid -> h, next-ln -> a or final ln -> out)
        mgemm_k<<<dim3(6, 13, 4), 256, 0, stream>>>(mb, W2, Cp, 768, 3072, 768);
        if (i < 11)
            ep_ln_k<false><<<Sn, 256, 0, stream>>>(Cp, fc2_b + i * Dm, h, ln1_g + (i + 1) * Dm, ln1_b + (i + 1) * Dm, a, 4);
        else
            ep_ln_k<true><<<Sn, 256, 0, stream>>>(Cp, fc2_b + i * Dm, h, lnf_g, lnf_b, d_out, 4);
    }
}

// Round 3
// 2279.321 us; speedup vs baseline: 1.0748x; 1.0395x over previous
//
#include <hip/hip_runtime.h>
#include <math.h>

#define Dm 768
#define Tn 8
#define Nn 197
#define Sn 1576
#define MLPn 3072
#define NPn 196
#define MPAD 1664   // 13*128 = 26*64

typedef unsigned short u16;
typedef __bf16 bf16x8 __attribute__((ext_vector_type(8)));
typedef float f32x4 __attribute__((ext_vector_type(4)));
typedef unsigned int u32x4 __attribute__((ext_vector_type(4)));
typedef u16 u16x8 __attribute__((ext_vector_type(8)));
typedef u16 u16x4 __attribute__((ext_vector_type(4)));

__device__ inline u16 f2bf(float f) {
    union { float f; unsigned u; } v; v.f = f;
    unsigned r = v.u + 0x7fffu + ((v.u >> 16) & 1u);
    return (u16)(r >> 16);
}
__device__ inline float bf2f(u16 v) {
    union { unsigned u; float f; } x; x.u = ((unsigned)v) << 16; return x.f;
}

// async global->LDS, 16B per lane. LDS dest is wave-uniform base + lane*16.
__device__ __forceinline__ void gl_lds16(const u16* __restrict__ g, u16* l) {
    __builtin_amdgcn_global_load_lds((const __attribute__((address_space(1))) void*)g,
                                     (__attribute__((address_space(3))) void*)l,
                                     16, 0, 0);
}

// ---------------- im2col: x[1,8,3,224,224] -> P[1568,768] bf16 ----------------
__global__ __launch_bounds__(256) void im2col_k(const float* __restrict__ x, u16* __restrict__ P) {
    int idx = blockIdx.x * 256 + threadIdx.x;
    if (idx >= 1568 * 768) return;
    int c = idx % 768, r = idx / 768;
    int p = r % 196, t = r / 196;
    int hp = p / 14, wp = p % 14;
    int ch = c / 256, rem = c % 256, py = rem / 16, px = rem % 16;
    P[idx] = f2bf(x[((t * 3 + ch) * 224 + hp * 16 + py) * 224 + wp * 16 + px]);
}

__global__ __launch_bounds__(256) void cvt_k(const float* __restrict__ s, u16* __restrict__ d, int n) {
    int i = blockIdx.x * 256 + threadIdx.x;
    if (i < n) d[i] = f2bf(s[i]);
}

// ---------------- per-layer weight transpose+convert: fp32 [K,N] -> bf16 [N,K] ----------------
__global__ __launch_bounds__(256) void cvtT_layer_k(const float* __restrict__ qw, const float* __restrict__ pw,
                                                    const float* __restrict__ f1w, const float* __restrict__ f2w,
                                                    u16* __restrict__ Wq, u16* __restrict__ Wp,
                                                    u16* __restrict__ W1, u16* __restrict__ W2) {
    __shared__ float tile[32][33];
    int bid = blockIdx.x;
    const float* src; u16* dst; int K, N, k0, n0;
    if (bid < 1728)      { src = qw;  dst = Wq; K = 768;  N = 2304; int r = bid;        k0 = (r / 72) * 32; n0 = (r % 72) * 32; }
    else if (bid < 2304) { src = pw;  dst = Wp; K = 768;  N = 768;  int r = bid - 1728; k0 = (r / 24) * 32; n0 = (r % 24) * 32; }
    else if (bid < 4608) { src = f1w; dst = W1; K = 768;  N = 3072; int r = bid - 2304; k0 = (r / 96) * 32; n0 = (r % 96) * 32; }
    else                 { src = f2w; dst = W2; K = 3072; N = 768;  int r = bid - 4608; k0 = (r / 24) * 32; n0 = (r % 24) * 32; }
    int tx = threadIdx.x & 31, ty = threadIdx.x >> 5;
#pragma unroll
    for (int i = 0; i < 4; ++i) tile[ty + 8 * i][tx] = src[(size_t)(k0 + ty + 8 * i) * N + n0 + tx];
    __syncthreads();
#pragma unroll
    for (int i = 0; i < 4; ++i) dst[(size_t)(n0 + ty + 8 * i) * K + k0 + tx] = f2bf(tile[tx][ty + 8 * i]);
}

// ---------------- scramble + cls + pos -> h[1576,768] fp32 ----------------
__global__ __launch_bounds__(256) void build_h_k(const float* __restrict__ emb, const float* __restrict__ cls,
                                                 const float* __restrict__ pos, float* __restrict__ h) {
    int idx = blockIdx.x * 256 + threadIdx.x;
    if (idx >= Sn * Dm) return;
    int d = idx % Dm, s = idx / Dm;
    int t = s / Nn, r = s % Nn;
    float v;
    if (r == 0) v = cls[d];
    else {
        int f = (r - 1) * Dm + d;
        int p = f % NPn, dd = f / NPn;
        v = emb[(size_t)(t * NPn + p) * Dm + dd];
    }
    h[idx] = v + pos[r * Dm + d];
}

// ---------------- LayerNorm (standalone; used once after build_h) ----------------
template <typename OutT>
__global__ __launch_bounds__(256) void ln_k(const float* __restrict__ X, const float* __restrict__ g,
                                            const float* __restrict__ bta, OutT* __restrict__ Y) {
    int row = blockIdx.x;
    const float* x = X + (size_t)row * Dm;
    float s = 0.f, s2 = 0.f;
#pragma unroll
    for (int q = 0; q < 3; ++q) {
        float v = x[threadIdx.x + q * 256];
        s += v; s2 += v * v;
    }
#pragma unroll
    for (int off = 1; off < 64; off <<= 1) {
        s  += __shfl_xor(s,  off);
        s2 += __shfl_xor(s2, off);
    }
    __shared__ float red[8];
    int wv = threadIdx.x >> 6;
    if ((threadIdx.x & 63) == 0) { red[wv * 2] = s; red[wv * 2 + 1] = s2; }
    __syncthreads();
    s  = red[0] + red[2] + red[4] + red[6];
    s2 = red[1] + red[3] + red[5] + red[7];
    float mu  = s * (1.f / 768.f);
    float var = s2 * (1.f / 768.f) - mu * mu;
    float rstd = rsqrtf(var + 1e-5f);
#pragma unroll
    for (int q = 0; q < 3; ++q) {
        int i = threadIdx.x + q * 256;
        float v = (x[i] - mu) * rstd * g[i] + bta[i];
        if constexpr (sizeof(OutT) == 2) Y[(size_t)row * Dm + i] = f2bf(v);
        else                             Y[(size_t)row * Dm + i] = v;
    }
}

// ---------------- split-K MFMA GEMM (proj / fc2 / patch), 2-phase dbuf pipeline ----------------
__global__ __launch_bounds__(256) void mgemm_k(const u16* __restrict__ A, const u16* __restrict__ Bt,
                                               float* __restrict__ Cp, int N, int Kfull, int Kc) {
    __shared__ __align__(16) u16 As[2 * 4096];
    __shared__ __align__(16) u16 Bs[2 * 4096];
    int split = blockIdx.z;
    A  += split * Kc;
    Bt += split * Kc;
    Cp += (size_t)split * MPAD * N;
    int tid = threadIdx.x;
    int lane = tid & 63, w = tid >> 6;
    int wm = w & 1, wn = w >> 1;
    int m0 = blockIdx.y * 128, n0 = blockIdx.x * 128;
    f32x4 acc[4][4] = {};
    int c0 = tid, c1 = tid + 256;
    int ar0 = ((c0 >> 6) << 4) + (c0 & 15), ac0 = ((c0 >> 4) & 3) << 3;
    int ar1 = ((c1 >> 6) << 4) + (c1 & 15), ac1 = ((c1 >> 4) & 3) << 3;
    const u16* Arow0 = A  + (size_t)(m0 + ar0) * Kfull + ac0;
    const u16* Arow1 = A  + (size_t)(m0 + ar1) * Kfull + ac1;
    const u16* Brow0 = Bt + (size_t)(n0 + ar0) * Kfull + ac0;
    const u16* Brow1 = Bt + (size_t)(n0 + ar1) * Kfull + ac1;
    // wave-uniform LDS bases (chunk base*8 u16 = *16 bytes); buf offset 4096 u16 = 8 KB
    auto STAGE = [&](int buf, int k0) {
        int bo = buf << 12;
        gl_lds16(Arow0 + k0, As + bo + (w * 64) * 8);
        gl_lds16(Arow1 + k0, As + bo + (256 + w * 64) * 8);
        gl_lds16(Brow0 + k0, Bs + bo + (w * 64) * 8);
        gl_lds16(Brow1 + k0, Bs + bo + (256 + w * 64) * 8);
    };
    STAGE(0, 0);
    asm volatile("s_waitcnt vmcnt(0)" ::: "memory");
    __builtin_amdgcn_s_barrier();
    int cur = 0;
    for (int k0 = 0; k0 < Kc; k0 += 32) {
        if (k0 + 32 < Kc) STAGE(cur ^ 1, k0 + 32);
        const u16* Ab = As + (cur << 12);
        const u16* Bb = Bs + (cur << 12);
        bf16x8 af[4], bfr[4];
#pragma unroll
        for (int i = 0; i < 4; ++i) {
            af[i]  = *(const bf16x8*)(Ab + (((wm * 4 + i) * 64 + lane) << 3));
            bfr[i] = *(const bf16x8*)(Bb + (((wn * 4 + i) * 64 + lane) << 3));
        }
#pragma unroll
        for (int mi = 0; mi < 4; ++mi)
#pragma unroll
            for (int ni = 0; ni < 4; ++ni)
                acc[mi][ni] = __builtin_amdgcn_mfma_f32_16x16x32_bf16(af[mi], bfr[ni], acc[mi][ni], 0, 0, 0);
        asm volatile("s_waitcnt vmcnt(0)" ::: "memory");
        __builtin_amdgcn_s_barrier();
        cur ^= 1;
    }
    int rbase = (lane >> 4) << 2, cl = lane & 15;
#pragma unroll
    for (int mi = 0; mi < 4; ++mi)
#pragma unroll
        for (int r = 0; r < 4; ++r) {
            int gm = m0 + wm * 64 + mi * 16 + rbase + r;
#pragma unroll
            for (int ni = 0; ni < 4; ++ni) {
                int gn = n0 + wn * 64 + ni * 16 + cl;
                Cp[(size_t)gm * N + gn] = acc[mi][ni][r];
            }
        }
}

// ---------------- fused no-split GEMM (qkv / fc1): 64x128 tile, 2-phase dbuf, bias[+gelu] -> bf16 ----------------
template <bool GELU_ACT>
__global__ __launch_bounds__(256) void mgemm_fused_k(const u16* __restrict__ A, const u16* __restrict__ Bt,
                                                     const float* __restrict__ bias, u16* __restrict__ out,
                                                     int N, int Kfull, int Mout) {
    __shared__ __align__(16) u16 As[2 * 64 * 32];    // 2 x 4 KB
    __shared__ __align__(16) u16 Bs[2 * 128 * 32];   // 2 x 8 KB
    int tid = threadIdx.x;
    int lane = tid & 63, w = tid >> 6;
    int wm = w & 1, wn = w >> 1;
    int m0 = blockIdx.y * 64, n0 = blockIdx.x * 128;
    f32x4 acc[2][4] = {};
    int ca = tid;
    int ar = ((ca >> 6) << 4) + (ca & 15), ac = ((ca >> 4) & 3) << 3;
    const u16* Arow = A + (size_t)(m0 + ar) * Kfull + ac;
    int cb1 = tid + 256;
    int br1 = ((cb1 >> 6) << 4) + (cb1 & 15), bc1 = ((cb1 >> 4) & 3) << 3;
    const u16* Brow0 = Bt + (size_t)(n0 + ar) * Kfull + ac;
    const u16* Brow1 = Bt + (size_t)(n0 + br1) * Kfull + bc1;
    auto STAGE = [&](int buf, int k0) {
        gl_lds16(Arow + k0, As + (buf << 11) + (w * 64) * 8);
        gl_lds16(Brow0 + k0, Bs + (buf << 12) + (w * 64) * 8);
        gl_lds16(Brow1 + k0, Bs + (buf << 12) + (256 + w * 64) * 8);
    };
    STAGE(0, 0);
    asm volatile("s_waitcnt vmcnt(0)" ::: "memory");
    __builtin_amdgcn_s_barrier();
    int cur = 0;
    for (int k0 = 0; k0 < Kfull; k0 += 32) {
        if (k0 + 32 < Kfull) STAGE(cur ^ 1, k0 + 32);
        const u16* Ab = As + (cur << 11);
        const u16* Bb = Bs + (cur << 12);
        bf16x8 af[2], bfr[4];
#pragma unroll
        for (int i = 0; i < 2; ++i) af[i]  = *(const bf16x8*)(Ab + (((wm * 2 + i) * 64 + lane) << 3));
#pragma unroll
        for (int j = 0; j < 4; ++j) bfr[j] = *(const bf16x8*)(Bb + (((wn * 4 + j) * 64 + lane) << 3));
#pragma unroll
        for (int mi = 0; mi < 2; ++mi)
#pragma unroll
            for (int ni = 0; ni < 4; ++ni)
                acc[mi][ni] = __builtin_amdgcn_mfma_f32_16x16x32_bf16(af[mi], bfr[ni], acc[mi][ni], 0, 0, 0);
        asm volatile("s_waitcnt vmcnt(0)" ::: "memory");
        __builtin_amdgcn_s_barrier();
        cur ^= 1;
    }
    int rbase = (lane >> 4) << 2, cl = lane & 15;
#pragma unroll
    for (int mi = 0; mi < 2; ++mi)
#pragma unroll
        for (int r = 0; r < 4; ++r) {
            int gm = m0 + wm * 32 + mi * 16 + rbase + r;
            if (gm < Mout) {
#pragma unroll
                for (int ni = 0; ni < 4; ++ni) {
                    int gn = n0 + wn * 64 + ni * 16 + cl;
                    float v = acc[mi][ni][r] + bias[gn];
                    if (GELU_ACT) v = 0.5f * v * (1.f + erff(v * 0.7071067811865476f));
                    out[(size_t)gm * N + gn] = f2bf(v);
                }
            }
        }
}

// ---------------- epilogue (patch embed only): sum splits + bias -> fp32 ----------------
__global__ __launch_bounds__(256) void ep_k(const float* __restrict__ Cp, const float* __restrict__ bias,
                                            float* __restrict__ out, int N, int S) {
    int row = blockIdx.y;
    int n = blockIdx.x * 1024 + threadIdx.x * 4;
    if (n >= N) return;
    size_t off = (size_t)row * N + n;
    f32x4 acc = *(const f32x4*)(Cp + off);
    for (int s = 1; s < S; ++s)
        acc += *(const f32x4*)(Cp + (size_t)s * MPAD * N + off);
    acc += *(const f32x4*)(bias + n);
    *(f32x4*)(out + off) = acc;
}

// ---------------- fused epilogue (proj / fc2): sum splits + bias + resid -> h, then LN -> lnout ----------------
template <bool FINALOUT>
__global__ __launch_bounds__(256) void ep_ln_k(const float* __restrict__ Cp, const float* __restrict__ bias,
                                               float* __restrict__ h, const float* __restrict__ g,
                                               const float* __restrict__ bta, void* __restrict__ lnout, int S) {
    int row = blockIdx.x;
    int t = threadIdx.x;
    float v[3];
    float s = 0.f, s2 = 0.f;
#pragma unroll
    for (int q = 0; q < 3; ++q) {
        int i = t + q * 256;
        size_t off = (size_t)row * Dm + i;
        float a = Cp[off];
        for (int sp = 1; sp < S; ++sp) a += Cp[(size_t)sp * MPAD * Dm + off];
        a += bias[i] + h[off];
        h[off] = a;
        v[q] = a; s += a; s2 += a * a;
    }
#pragma unroll
    for (int off = 1; off < 64; off <<= 1) {
        s  += __shfl_xor(s,  off);
        s2 += __shfl_xor(s2, off);
    }
    __shared__ float red[8];
    int wv = t >> 6;
    if ((t & 63) == 0) { red[wv * 2] = s; red[wv * 2 + 1] = s2; }
    __syncthreads();
    s  = red[0] + red[2] + red[4] + red[6];
    s2 = red[1] + red[3] + red[5] + red[7];
    float mu  = s * (1.f / 768.f);
    float var = s2 * (1.f / 768.f) - mu * mu;
    float rstd = rsqrtf(var + 1e-5f);
#pragma unroll
    for (int q = 0; q < 3; ++q) {
        int i = t + q * 256;
        float y = (v[q] - mu) * rstd * g[i] + bta[i];
        if constexpr (FINALOUT) ((float*)lnout)[(size_t)row * Dm + i] = y;
        else                    ((u16*)lnout)[(size_t)row * Dm + i] = f2bf(y);
    }
}

// ---------------- per-(head,frame) mean of V (bf16 input), 4-wave ----------------
__global__ __launch_bounds__(256) void vmean_k(const u16* __restrict__ qkv, float* __restrict__ vm) {
    int g = blockIdx.x;      // g = h*8 + t
    int h = g >> 3, t = g & 7;
    int d = threadIdx.x & 63, part = threadIdx.x >> 6;
    float s = 0.f;
    for (int n = part; n < Nn; n += 4)
        s += bf2f(qkv[(size_t)(t * Nn + n) * 2304 + 1536 + h * 64 + d]);
    __shared__ float red[256];
    red[threadIdx.x] = s;
    __syncthreads();
    if (part == 0) vm[g * 64 + d] = (red[d] + red[64 + d] + red[128 + d] + red[192 + d]) * (1.f / 197.f);
}

// ---------------- MFMA flash attention ----------------
// fuse=1 (even layers, nsplit==1): normalize + vmean in-kernel, write bf16 ob directly.
__global__ __launch_bounds__(256) void attn_mfma_k(const u16* __restrict__ qkv, float* __restrict__ Ou,
                                                   float* __restrict__ ml, const float* __restrict__ vm,
                                                   u16* __restrict__ ob, int even, int nsplit,
                                                   int NG, int Sq, int fuse) {
    __shared__ __align__(16) u16 Ks[64 * 64];
    __shared__ __align__(16) u16 Vt[64 * 64];
    __shared__ __align__(16) u16 Ps[4 * 32 * 64];
    int g = blockIdx.y;
    int h, sbase;
    if (even) { h = g >> 3; sbase = (g & 7) * Nn; } else { h = g; sbase = 0; }
    int split = blockIdx.z;
    int chunk = (Sq + nsplit - 1) / nsplit;
    int kbeg = split * chunk, kend = min(Sq, kbeg + chunk);
    int tid = threadIdx.x, lane = tid & 63, w = tid >> 6;
    int quad = lane >> 4, l15 = lane & 15;
    int q0w = blockIdx.x * 128 + w * 32;
    u16* Pw = Ps + w * 2048;

    bf16x8 aq[2][2];
#pragma unroll
    for (int mb = 0; mb < 2; ++mb) {
        int qidx = q0w + mb * 16 + l15; if (qidx >= Sq) qidx = Sq - 1;
        const u16* qp = qkv + (size_t)(sbase + qidx) * 2304 + h * 64;
#pragma unroll
        for (int ks = 0; ks < 2; ++ks)
            aq[mb][ks] = *(const bf16x8*)(qp + ks * 32 + quad * 8);
    }
    f32x4 acc_o[2][4] = {};
    float m_run[2][4], l_run[2][4];
#pragma unroll
    for (int mb = 0; mb < 2; ++mb)
#pragma unroll
        for (int r = 0; r < 4; ++r) { m_run[mb][r] = -INFINITY; l_run[mb][r] = 0.f; }

    for (int kt = kbeg; kt < kend; kt += 64) {
        int cnt = kend - kt; if (cnt > 64) cnt = 64;
        {
            int dc = tid & 7;
#pragma unroll
            for (int p = 0; p < 2; ++p) {
                int row = (tid >> 3) + 32 * p;
                u32x4 kd = {};
                if (row < cnt) kd = *(const u32x4*)(qkv + (size_t)(sbase + kt + row) * 2304 + 768 + h * 64 + dc * 8);
                *(u32x4*)(Ks + row * 64 + ((dc ^ (row & 7)) << 3)) = kd;
            }
        }
        {
            int d = (tid & 31) * 2, kc = tid >> 5;
            u16x8 lo, hi;
#pragma unroll
            for (int i = 0; i < 8; ++i) {
                int key = kc * 8 + i;
                unsigned t = 0;
                if (key < cnt) t = *(const unsigned*)(qkv + (size_t)(sbase + kt + key) * 2304 + 1536 + h * 64 + d);
                lo[i] = (u16)(t & 0xffffu); hi[i] = (u16)(t >> 16);
            }
            *(u16x8*)(Vt + d * 64 + ((kc ^ (d & 7)) << 3)) = lo;
            *(u16x8*)(Vt + (d + 1) * 64 + ((kc ^ ((d + 1) & 7)) << 3)) = hi;
        }
        __syncthreads();
        f32x4 acc_s[2][4] = {};
#pragma unroll
        for (int ni = 0; ni < 4; ++ni) {
            int key = l15 + ni * 16;
#pragma unroll
            for (int ks = 0; ks < 2; ++ks) {
                bf16x8 bk = *(const bf16x8*)(Ks + key * 64 + ((((ks << 2) + quad) ^ (key & 7)) << 3));
                acc_s[0][ni] = __builtin_amdgcn_mfma_f32_16x16x32_bf16(aq[0][ks], bk, acc_s[0][ni], 0, 0, 0);
                acc_s[1][ni] = __builtin_amdgcn_mfma_f32_16x16x32_bf16(aq[1][ks], bk, acc_s[1][ni], 0, 0, 0);
            }
        }
#pragma unroll
        for (int mb = 0; mb < 2; ++mb) {
#pragma unroll
            for (int ni = 0; ni < 4; ++ni) {
                int keyabs = kt + l15 + ni * 16;
#pragma unroll
                for (int r = 0; r < 4; ++r) {
                    float sv = acc_s[mb][ni][r] * 0.125f;
                    if (keyabs >= kend) sv = -1e30f;
                    acc_s[mb][ni][r] = sv;
                }
            }
#pragma unroll
            for (int r = 0; r < 4; ++r) {
                float mx = fmaxf(fmaxf(acc_s[mb][0][r], acc_s[mb][1][r]), fmaxf(acc_s[mb][2][r], acc_s[mb][3][r]));
                mx = fmaxf(mx, __shfl_xor(mx, 1));
                mx = fmaxf(mx, __shfl_xor(mx, 2));
                mx = fmaxf(mx, __shfl_xor(mx, 4));
                mx = fmaxf(mx, __shfl_xor(mx, 8));
                float mnew = fmaxf(m_run[mb][r], mx);
                float pv[4], ps = 0.f;
#pragma unroll
                for (int ni = 0; ni < 4; ++ni) { pv[ni] = __expf(acc_s[mb][ni][r] - mnew); ps += pv[ni]; }
                ps += __shfl_xor(ps, 1);
                ps += __shfl_xor(ps, 2);
                ps += __shfl_xor(ps, 4);
                ps += __shfl_xor(ps, 8);
                float alpha = __expf(m_run[mb][r] - mnew);
                l_run[mb][r] = l_run[mb][r] * alpha + ps;
                m_run[mb][r] = mnew;
#pragma unroll
                for (int ni = 0; ni < 4; ++ni) acc_o[mb][ni][r] *= alpha;
                int prow = mb * 16 + quad * 4 + r;
#pragma unroll
                for (int ni = 0; ni < 4; ++ni) {
                    int key = l15 + ni * 16;
                    Pw[prow * 64 + (((key >> 3) ^ (prow & 7)) << 3) + (key & 7)] = f2bf(pv[ni]);
                }
            }
        }
        bf16x8 ap[2][2];
#pragma unroll
        for (int mb = 0; mb < 2; ++mb)
#pragma unroll
            for (int ks = 0; ks < 2; ++ks)
                ap[mb][ks] = *(const bf16x8*)(Pw + (mb * 16 + l15) * 64 + ((((ks << 2) + quad) ^ (l15 & 7)) << 3));
#pragma unroll
        for (int ni = 0; ni < 4; ++ni) {
            int d = l15 + ni * 16;
#pragma unroll
            for (int ks = 0; ks < 2; ++ks) {
                bf16x8 bv = *(const bf16x8*)(Vt + d * 64 + ((((ks << 2) + quad) ^ (d & 7)) << 3));
                acc_o[0][ni] = __builtin_amdgcn_mfma_f32_16x16x32_bf16(ap[0][ks], bv, acc_o[0][ni], 0, 0, 0);
                acc_o[1][ni] = __builtin_amdgcn_mfma_f32_16x16x32_bf16(ap[1][ks], bv, acc_o[1][ni], 0, 0, 0);
            }
        }
        __syncthreads();
    }
    if (fuse) {
        // single split: normalize, add vmean, write bf16 directly
#pragma unroll
        for (int mb = 0; mb < 2; ++mb)
#pragma unroll
            for (int r = 0; r < 4; ++r) {
                int q = q0w + mb * 16 + quad * 4 + r;
                if (q < Sq) {
                    float inv = 1.f / l_run[mb][r];
                    u16* op = ob + (size_t)(sbase + q) * Dm + h * 64;
#pragma unroll
                    for (int ni = 0; ni < 4; ++ni) {
                        int d = l15 + ni * 16;
                        op[d] = f2bf(acc_o[mb][ni][r] * inv + vm[g * 64 + d]);
                    }
                }
            }
    } else {
        size_t gb = ((size_t)split * NG + g) * Sq;
#pragma unroll
        for (int mb = 0; mb < 2; ++mb)
#pragma unroll
            for (int r = 0; r < 4; ++r) {
                int q = q0w + mb * 16 + quad * 4 + r;
                if (q < Sq) {
                    float* op = Ou + (gb + q) * 64;
#pragma unroll
                    for (int ni = 0; ni < 4; ++ni) op[l15 + ni * 16] = acc_o[mb][ni][r];
                    if (l15 == 0) {
                        ml[(gb + q) * 2]     = m_run[mb][r];
                        ml[(gb + q) * 2 + 1] = l_run[mb][r];
                    }
                }
            }
    }
}

// ---------------- combine splits (odd layers) -> ob bf16 ----------------
__global__ __launch_bounds__(256) void comb_k(const float* __restrict__ Ou, const float* __restrict__ ml,
                                              u16* __restrict__ ob, int nsplit, int NG, int Sq) {
    int g = blockIdx.y;
    int q = blockIdx.x * 4 + (threadIdx.x >> 6);
    int d = threadIdx.x & 63;
    if (q >= Sq) return;
    int h = g, sbase = 0;
    float M = -INFINITY;
    for (int s = 0; s < nsplit; ++s) M = fmaxf(M, ml[(((size_t)s * NG + g) * Sq + q) * 2]);
    float num = 0.f, den = 0.f;
    for (int s = 0; s < nsplit; ++s) {
        size_t base = ((size_t)s * NG + g) * Sq + q;
        float wgt = __expf(ml[base * 2] - M);
        den += wgt * ml[base * 2 + 1];
        num += wgt * Ou[base * 64 + d];
    }
    float o = num / den;
    ob[(size_t)(sbase + q) * Dm + h * 64 + d] = f2bf(o);
}

extern "C" void kernel_launch(void* const* d_in, const int* in_sizes, int n_in,
                              void* d_out, int out_size, void* d_ws, size_t ws_size,
                              hipStream_t stream) {
    (void)in_sizes; (void)n_in; (void)out_size; (void)ws_size;
    const float* x       = (const float*)d_in[0];
    const float* W_patch = (const float*)d_in[1];
    const float* b_patch = (const float*)d_in[2];
    const float* cls     = (const float*)d_in[3];
    const float* pos     = (const float*)d_in[4];
    const float* ln1_g   = (const float*)d_in[5];
    const float* ln1_b   = (const float*)d_in[6];
    const float* qkv_w   = (const float*)d_in[7];
    const float* qkv_b   = (const float*)d_in[8];
    const float* proj_w  = (const float*)d_in[9];
    const float* proj_b  = (const float*)d_in[10];
    const float* ln2_g   = (const float*)d_in[11];
    const float* ln2_b   = (const float*)d_in[12];
    const float* fc1_w   = (const float*)d_in[13];
    const float* fc1_b   = (const float*)d_in[14];
    const float* fc2_w   = (const float*)d_in[15];
    const float* fc2_b   = (const float*)d_in[16];
    const float* lnf_g   = (const float*)d_in[17];
    const float* lnf_b   = (const float*)d_in[18];

    char* base = (char*)d_ws;
    auto alloc = [&](size_t bytes) { void* p = base; base += (bytes + 255) & ~(size_t)255; return p; };
    u16*   P    = (u16*)  alloc((size_t)MPAD * 768 * 2);
    u16*   Wq   = (u16*)  alloc((size_t)2304 * 768 * 2);
    u16*   Wp   = (u16*)  alloc((size_t)768 * 768 * 2);
    u16*   W1   = (u16*)  alloc((size_t)3072 * 768 * 2);
    u16*   W2   = (u16*)  alloc((size_t)768 * 3072 * 2);
    float* emb  = (float*)alloc((size_t)1568 * 768 * 4);
    float* h    = (float*)alloc((size_t)Sn * Dm * 4);
    u16*   a    = (u16*)  alloc((size_t)MPAD * 768 * 2);
    u16*   qkvb = (u16*)  alloc((size_t)Sn * 2304 * 2);
    u16*   ob   = (u16*)  alloc((size_t)MPAD * 768 * 2);
    u16*   mb   = (u16*)  alloc((size_t)MPAD * 3072 * 2);
    float* vm   = (float*)alloc((size_t)96 * 64 * 4);
    float* Ou   = (float*)alloc((size_t)3 * 12 * Sn * 64 * 4);
    float* ml   = (float*)alloc((size_t)3 * 12 * Sn * 2 * 4);
    float* Cp   = (float*)alloc((size_t)4 * MPAD * 768 * 4);   // split-K partials (proj/fc2/patch)

    // ---- patch embed ----
    im2col_k<<<(1568 * 768 + 255) / 256, 256, 0, stream>>>(x, P);
    cvt_k<<<(768 * 768 + 255) / 256, 256, 0, stream>>>(W_patch, Wp, 768 * 768);
    mgemm_k<<<dim3(6, 13, 3), 256, 0, stream>>>(P, Wp, Cp, 768, 768, 256);
    ep_k<<<dim3(1, 1568), 256, 0, stream>>>(Cp, b_patch, emb, 768, 3);
    build_h_k<<<(Sn * Dm + 255) / 256, 256, 0, stream>>>(emb, cls, pos, h);
    ln_k<u16><<<Sn, 256, 0, stream>>>(h, ln1_g, ln1_b, a);   // layer-0 ln1

    for (int i = 0; i < 12; ++i) {
        cvtT_layer_k<<<6912, 256, 0, stream>>>(
            qkv_w + (size_t)i * 768 * 2304, proj_w + (size_t)i * 768 * 768,
            fc1_w + (size_t)i * 768 * 3072, fc2_w + (size_t)i * 3072 * 768,
            Wq, Wp, W1, W2);
        // qkv: fused no-split GEMM, bias -> bf16
        mgemm_fused_k<false><<<dim3(18, 26), 256, 0, stream>>>(a, Wq, qkv_b + i * 2304, qkvb, 2304, 768, Sn);
        if ((i & 1) == 0) {
            vmean_k<<<96, 256, 0, stream>>>(qkvb, vm);
            attn_mfma_k<<<dim3(2, 96, 1), 256, 0, stream>>>(qkvb, Ou, ml, vm, ob, 1, 1, 96, Nn, 1);
        } else {
            attn_mfma_k<<<dim3(13, 12, 3), 256, 0, stream>>>(qkvb, Ou, ml, vm, ob, 0, 3, 12, Sn, 0);
            comb_k<<<dim3(394, 12), 256, 0, stream>>>(Ou, ml, ob, 3, 12, Sn);
        }
        // proj: split-K GEMM + fused (bias+resid -> h, ln2 -> a)
        mgemm_k<<<dim3(6, 13, 4), 256, 0, stream>>>(ob, Wp, Cp, 768, 768, 192);
        ep_ln_k<false><<<Sn, 256, 0, stream>>>(Cp, proj_b + i * Dm, h, ln2_g + i * Dm, ln2_b + i * Dm, a, 4);
        // fc1: fused no-split GEMM, bias+gelu -> bf16
        mgemm_fused_k<true><<<dim3(24, 26), 256, 0, stream>>>(a, W1, fc1_b + i * MLPn, mb, 3072, 768, Sn);
        // fc2: split-K GEMM + fused (bias+resid -> h, next-ln -> a or final ln -> out)
        mgemm_k<<<dim3(6, 13, 4), 256, 0, stream>>>(mb, W2, Cp, 768, 3072, 768);
        if (i < 11)
            ep_ln_k<false><<<Sn, 256, 0, stream>>>(Cp, fc2_b + i * Dm, h, ln1_g + (i + 1) * Dm, ln1_b + (i + 1) * Dm, a, 4);
        else
            ep_ln_k<true><<<Sn, 256, 0, stream>>>(Cp, fc2_b + i * Dm, h, lnf_g, lnf_b, d_out, 4);
    }
}